// Round 9
// baseline (264.625 us; speedup 1.0000x reference)
//
#include <hip/hip_runtime.h>
#include <math.h>

#define BB 8
#define NN 256
#define DD 512
#define HH 16
#define KK 4
#define DKK 32
#define FFN_ 2048
#define NEGV -1e12f

typedef __attribute__((ext_vector_type(8))) short bf16x8;
typedef __attribute__((ext_vector_type(4))) float f32x4;

__device__ __forceinline__ unsigned short f2bf(float f) {
    union { float f; unsigned int u; } v; v.f = f;
    unsigned int r = (v.u + 0x7FFFu + ((v.u >> 16) & 1u)) >> 16;
    return (unsigned short)r;
}
__device__ __forceinline__ float bf2f(unsigned short u) {
    union { unsigned int i; float f; } v; v.i = ((unsigned int)u) << 16;
    return v.f;
}
__device__ __forceinline__ void gload_lds16(const unsigned short* g, unsigned short* l) {
    __builtin_amdgcn_global_load_lds(
        (const __attribute__((address_space(1))) void*)g,
        (__attribute__((address_space(3))) void*)l, 16, 0, 0);
}

// ---------------------------------------------------------------------------
// Merged prep (R4-proven): z=0..6 weight transposes fp32->bf16 Wt[N][K];
// z=7 x->bf16; z=8 bias concat; z=9 mask+dist+bias combine (biasMs).
// ---------------------------------------------------------------------------
__global__ __launch_bounds__(256) void prep_kernel(
    const float* __restrict__ x,
    const float* __restrict__ Wq, const float* __restrict__ Wk,
    const float* __restrict__ Wv, const float* __restrict__ W1,
    const float* __restrict__ W2, const float* __restrict__ Wf1,
    const float* __restrict__ Wf2,
    const float* __restrict__ bq, const float* __restrict__ bk,
    const float* __restrict__ bv,
    const float* __restrict__ attn_bias, const int* __restrict__ mask,
    const float* __restrict__ dist, const float* __restrict__ dist_bar,
    unsigned short* __restrict__ xb, unsigned short* __restrict__ Wqkvt,
    unsigned short* __restrict__ W1t, unsigned short* __restrict__ W2t,
    unsigned short* __restrict__ Wf1t, unsigned short* __restrict__ Wf2t,
    float* __restrict__ bqkv, unsigned short* __restrict__ biasMs)
{
    const int z = blockIdx.z;
    const int t = threadIdx.x;

    if (z == 7) {
        if (blockIdx.x >= 1024) return;
        const int i0 = blockIdx.x * 1024 + t * 4;
        float4 xv = *(const float4*)(x + i0);
        ushort4 o;
        o.x = f2bf(xv.x); o.y = f2bf(xv.y); o.z = f2bf(xv.z); o.w = f2bf(xv.w);
        *(ushort4*)(xb + i0) = o;
        return;
    }
    if (z == 8) {
        if (blockIdx.x >= 6) return;
        const int i = blockIdx.x * 256 + t;
        float v = (i < 512) ? bq[i] : (i < 1024) ? bk[i - 512] : bv[i - 1024];
        bqkv[i] = v;
        return;
    }
    if (z == 9) {
        const int bx = blockIdx.x;
        const int rg = bx & 63, ks = (bx >> 6) & 3, b = bx >> 8;
        const int m = t;
        const float bar = dist_bar[ks];
        ushort4 o; unsigned short* po = (unsigned short*)&o;
        #pragma unroll
        for (int i = 0; i < 4; ++i) {
            const int n = rg * 4 + i;
            const int mk = mask[((size_t)(b * NN) + n) * NN + m];
            bool allowed = (n == 0) || (m == 0);
            if (!allowed)
                allowed = dist[((size_t)(b * 255) + (n - 1)) * 255 + (m - 1)] < bar;
            const float bias = attn_bias[(((size_t)(b * KK) + ks) * NN + n) * NN + m];
            po[i] = f2bf((mk != 0 && allowed) ? bias : NEGV);
        }
        *(ushort4*)(biasMs + (size_t)bx * 1024 + m * 4) = o;
        return;
    }

    const float* src; unsigned short* dst; int Kd, Nd;
    switch (z) {
        case 0: src = Wq;  dst = Wqkvt;              Kd = 512;  Nd = 512;  break;
        case 1: src = Wk;  dst = Wqkvt + 512 * 512;  Kd = 512;  Nd = 512;  break;
        case 2: src = Wv;  dst = Wqkvt + 1024 * 512; Kd = 512;  Nd = 512;  break;
        case 3: src = W1;  dst = W1t;  Kd = 2048; Nd = 512;  break;
        case 4: src = W2;  dst = W2t;  Kd = 512;  Nd = 512;  break;
        case 5: src = Wf1; dst = Wf1t; Kd = 512;  Nd = 2048; break;
        default: src = Wf2; dst = Wf2t; Kd = 2048; Nd = 512; break;
    }
    const int ktiles = Kd / 32, ntiles = Nd / 32;
    const int ti = blockIdx.x;
    if (ti >= ktiles * ntiles) return;
    const int k0 = (ti % ktiles) * 32, n0 = (ti / ktiles) * 32;

    __shared__ float tile[32][33];
    const int xx = t & 31, yy = t >> 5;
    #pragma unroll
    for (int r = 0; r < 4; ++r)
        tile[yy * 4 + r][xx] = src[(size_t)(k0 + yy * 4 + r) * Nd + n0 + xx];
    __syncthreads();
    #pragma unroll
    for (int r = 0; r < 4; ++r)
        dst[(size_t)(n0 + yy * 4 + r) * Kd + k0 + xx] = f2bf(tile[xx][yy * 4 + r]);
}

// ---------------------------------------------------------------------------
// 512-thread 128x128 MFMA GEMM (R4-proven), 8 waves (4m x 2n), BK=64.
// EPI 0: bf16 out + ACT.  EPI 1: QKV split (col<1024 -> Cb pitch 1536, else
// vT transposed).
// ---------------------------------------------------------------------------
template<int ACT, int EPI>
__global__ __launch_bounds__(512) void mfma_gemm512(
    const unsigned short* __restrict__ A, const unsigned short* __restrict__ Bt,
    const float* __restrict__ bias, unsigned short* __restrict__ Cb,
    unsigned short* __restrict__ vT, int M, int N, int Kdim)
{
    __shared__ unsigned short As[128 * 64];
    __shared__ unsigned short Bs[128 * 64];

    const int t = threadIdx.x, lane = t & 63, wv = t >> 6;
    const int n0 = blockIdx.x * 128, m0 = blockIdx.y * 128;
    const int wm = wv >> 1, wn = wv & 1;
    const int L = lane & 15, qd = lane >> 4;
    const int sr = lane >> 3, sc = lane & 7;

    f32x4 acc[2][4];
    #pragma unroll
    for (int i = 0; i < 2; ++i)
        #pragma unroll
        for (int j = 0; j < 4; ++j) acc[i][j] = (f32x4){0.f, 0.f, 0.f, 0.f};

    for (int kt = 0; kt < Kdim; kt += 64) {
        #pragma unroll
        for (int p = 0; p < 2; ++p) {
            const int rbase = wv * 16 + p * 8;
            gload_lds16(A  + (size_t)(m0 + rbase + sr) * Kdim + kt + sc * 8,
                        As + rbase * 64);
            gload_lds16(Bt + (size_t)(n0 + rbase + sr) * Kdim + kt + sc * 8,
                        Bs + rbase * 64);
        }
        __syncthreads();
        #pragma unroll
        for (int s = 0; s < 2; ++s) {
            bf16x8 af[2], bfb[4];
            #pragma unroll
            for (int i = 0; i < 2; ++i)
                af[i] = *(const bf16x8*)(As + (wm * 32 + i * 16 + L) * 64 + s * 32 + qd * 8);
            #pragma unroll
            for (int j = 0; j < 4; ++j)
                bfb[j] = *(const bf16x8*)(Bs + (wn * 64 + j * 16 + L) * 64 + s * 32 + qd * 8);
            #pragma unroll
            for (int i = 0; i < 2; ++i)
                #pragma unroll
                for (int j = 0; j < 4; ++j)
                    acc[i][j] = __builtin_amdgcn_mfma_f32_16x16x32_bf16(af[i], bfb[j], acc[i][j], 0, 0, 0);
        }
        __syncthreads();
    }

    #pragma unroll
    for (int j = 0; j < 4; ++j) {
        const int col = n0 + wn * 64 + j * 16 + L;
        const float bv = bias[col];
        #pragma unroll
        for (int i = 0; i < 2; ++i) {
            const int rowb = m0 + wm * 32 + i * 16 + qd * 4;
            if (EPI == 1 && col >= 1024) {
                ushort4 pk; unsigned short* pp = (unsigned short*)&pk;
                #pragma unroll
                for (int r = 0; r < 4; ++r) pp[r] = f2bf(acc[i][j][r] + bv);
                *(ushort4*)(vT + (size_t)(col - 1024) * 2048 + rowb) = pk;
            } else {
                #pragma unroll
                for (int r = 0; r < 4; ++r) {
                    float v = acc[i][j][r] + bv;
                    if (ACT == 2) v = 0.5f * v * (1.0f + erff(v * 0.70710678118654752f));
                    Cb[(size_t)(rowb + r) * N + col] = f2bf(v);
                }
            }
        }
    }
}

// ---------------------------------------------------------------------------
// 512-thread 8-wave 64x64 MFMA GEMM (R6-mega-verified mapping, standalone).
// Wave grid 4m x 2n, wave = 16 rows x 32 cols, BK=64; 2 waves/SIMD at
// 256 blocks for latency hiding (the R8 4-wave version ran 1 wave/SIMD).
// ACT 1 = silu. OUTF32: fp32 out (Cf) else bf16 (Cb).
// ---------------------------------------------------------------------------
template<int ACT, int OUTF32>
__global__ __launch_bounds__(512) void mfma_gemm64w8(
    const unsigned short* __restrict__ A, const unsigned short* __restrict__ Bt,
    const float* __restrict__ bias, unsigned short* __restrict__ Cb,
    float* __restrict__ Cf, int M, int N, int Kdim)
{
    __shared__ unsigned short As[64 * 64];
    __shared__ unsigned short Bs[64 * 64];

    const int t = threadIdx.x, lane = t & 63, wv = t >> 6;
    const int wm = wv >> 1, wn = wv & 1;
    const int L = lane & 15, qd = lane >> 4;
    const int sr = lane >> 3, sc = lane & 7;
    const int n0 = blockIdx.x * 64, m0 = blockIdx.y * 64;

    f32x4 acc[2] = {(f32x4){0.f,0.f,0.f,0.f}, (f32x4){0.f,0.f,0.f,0.f}};

    for (int kt = 0; kt < Kdim; kt += 64) {
        gload_lds16(A  + (size_t)(m0 + wv * 8 + sr) * Kdim + kt + sc * 8,
                    As + wv * 8 * 64);
        gload_lds16(Bt + (size_t)(n0 + wv * 8 + sr) * Kdim + kt + sc * 8,
                    Bs + wv * 8 * 64);
        __syncthreads();
        #pragma unroll
        for (int s = 0; s < 2; ++s) {
            const bf16x8 a = *(const bf16x8*)(As + (wm * 16 + L) * 64 + s * 32 + qd * 8);
            #pragma unroll
            for (int j = 0; j < 2; ++j) {
                const bf16x8 b = *(const bf16x8*)(Bs + (wn * 32 + j * 16 + L) * 64 + s * 32 + qd * 8);
                acc[j] = __builtin_amdgcn_mfma_f32_16x16x32_bf16(a, b, acc[j], 0, 0, 0);
            }
        }
        __syncthreads();
    }

    #pragma unroll
    for (int j = 0; j < 2; ++j) {
        const int col = n0 + wn * 32 + j * 16 + L;
        const float bv = bias[col];
        #pragma unroll
        for (int r = 0; r < 4; ++r) {
            const int row = m0 + wm * 16 + qd * 4 + r;
            float v = acc[j][r] + bv;
            if (ACT == 1) v = v / (1.0f + __expf(-v));
            if (OUTF32) Cf[(size_t)row * N + col] = v;
            else        Cb[(size_t)row * N + col] = f2bf(v);
        }
    }
}

// ---------------------------------------------------------------------------
// Per-wave LayerNorm (barrier-free): 4 waves/block, wave = 1 row of 512.
// out = LN(a + r)*g + be.  OUT16: also write bf16 copy.
// ---------------------------------------------------------------------------
template<int OUT16>
__global__ __launch_bounds__(256) void ln_kernel(
    const float* __restrict__ a, const float* __restrict__ r,
    const float* __restrict__ g, const float* __restrict__ be,
    float* __restrict__ out, unsigned short* __restrict__ outb)
{
    const int t = threadIdx.x, lane = t & 63, wv = t >> 6;
    const int row = blockIdx.x * 4 + wv;
    const size_t base = (size_t)row * DD + lane * 8;
    const int c0 = lane * 8;

    float z[8]; float s = 0.f;
    #pragma unroll
    for (int i = 0; i < 8; ++i) { z[i] = a[base + i] + r[base + i]; s += z[i]; }
    #pragma unroll
    for (int off = 32; off > 0; off >>= 1) s += __shfl_xor(s, off);
    const float mean = s * (1.0f / 512.0f);
    float v = 0.f;
    #pragma unroll
    for (int i = 0; i < 8; ++i) { z[i] -= mean; v += z[i] * z[i]; }
    #pragma unroll
    for (int off = 32; off > 0; off >>= 1) v += __shfl_xor(v, off);
    const float inv = rsqrtf(v * (1.0f / 512.0f) + 1e-6f);

    unsigned short o16[8];
    #pragma unroll
    for (int i = 0; i < 8; ++i) {
        const float o = z[i] * inv * g[c0 + i] + be[c0 + i];
        out[base + i] = o;
        if (OUT16) o16[i] = f2bf(o);
    }
    if (OUT16) *(bf16x8*)(outb + base) = *(bf16x8*)o16;
}

// ---------------------------------------------------------------------------
// MFMA attention (R3/R4-proven): one block per (b, h, 64-query tile).
// ---------------------------------------------------------------------------
__global__ __launch_bounds__(256) void attn_kernel(
    const unsigned short* __restrict__ qkvb, const unsigned short* __restrict__ vT,
    const unsigned short* __restrict__ biasMs, unsigned short* __restrict__ msgT)
{
    const int qt = blockIdx.x, h = blockIdx.y, b = blockIdx.z;
    const int q0 = qt * 64;
    const int t = threadIdx.x, lane = t & 63, wv = t >> 6;
    const int L = lane & 15, qd = lane >> 4;

    __shared__ unsigned short Qs[64 * 32];
    __shared__ unsigned short Ks[256 * 32];
    __shared__ unsigned short Vs[32 * 264];
    __shared__ unsigned short Ps[64 * 264];
    __shared__ unsigned short Ot[32 * 72];

    {
        const int r = lane >> 2, c = lane & 3;
        gload_lds16(qkvb + (size_t)(b * NN + q0 + wv * 16 + r) * 1536 + h * DKK + c * 8,
                    Qs + wv * 16 * 32);
        #pragma unroll
        for (int p = 0; p < 4; ++p)
            gload_lds16(qkvb + (size_t)(b * NN + p * 64 + wv * 16 + r) * 1536 + 512 + h * DKK + c * 8,
                        Ks + (p * 64 + wv * 16) * 32);
    }
    {
        const int vr = t >> 3, seg = t & 7;
        const unsigned short* gv = vT + (size_t)(h * DKK + vr) * 2048 + b * NN + seg * 32;
        #pragma unroll
        for (int i = 0; i < 4; ++i) {
            bf16x8 vv = *(const bf16x8*)(gv + i * 8);
            *(bf16x8*)(Vs + vr * 264 + seg * 32 + i * 8) = vv;
        }
    }
    __syncthreads();

    f32x4 S[16];
    #pragma unroll
    for (int j = 0; j < 16; ++j) S[j] = (f32x4){0.f, 0.f, 0.f, 0.f};
    {
        const bf16x8 aq = *(const bf16x8*)(Qs + (wv * 16 + L) * 32 + qd * 8);
        #pragma unroll
        for (int j = 0; j < 16; ++j) {
            const bf16x8 bk = *(const bf16x8*)(Ks + (j * 16 + L) * 32 + qd * 8);
            S[j] = __builtin_amdgcn_mfma_f32_16x16x32_bf16(aq, bk, S[j], 0, 0, 0);
        }
    }
    const float scale = 0.17677669529663687f;
    const int rgb = (q0 + wv * 16) >> 2;

    for (int ks = 0; ks < KK; ++ks) {
        const unsigned short* bp = biasMs + ((size_t)((b * KK + ks) * 64 + rgb + qd)) * 1024;

        ushort4 b4[16];
        float mx[4] = {-3e38f, -3e38f, -3e38f, -3e38f};
        #pragma unroll
        for (int j = 0; j < 16; ++j) {
            b4[j] = *(const ushort4*)(bp + (j * 16 + L) * 4);
            const unsigned short* pb = (const unsigned short*)&b4[j];
            #pragma unroll
            for (int r = 0; r < 4; ++r)
                mx[r] = fmaxf(mx[r], S[j][r] * scale + bf2f(pb[r]));
        }
        #pragma unroll
        for (int off = 8; off > 0; off >>= 1)
            #pragma unroll
            for (int r = 0; r < 4; ++r) mx[r] = fmaxf(mx[r], __shfl_xor(mx[r], off));

        float sm[4] = {0.f, 0.f, 0.f, 0.f};
        #pragma unroll
        for (int j = 0; j < 16; ++j) {
            const unsigned short* pb = (const unsigned short*)&b4[j];
            #pragma unroll
            for (int r = 0; r < 4; ++r) {
                const float e = __expf(S[j][r] * scale + bf2f(pb[r]) - mx[r]);
                sm[r] += e;
                Ps[(wv * 16 + qd * 4 + r) * 264 + j * 16 + L] = f2bf(e);
            }
        }
        #pragma unroll
        for (int off = 8; off > 0; off >>= 1)
            #pragma unroll
            for (int r = 0; r < 4; ++r) sm[r] += __shfl_xor(sm[r], off);
        float inv[4];
        #pragma unroll
        for (int r = 0; r < 4; ++r) inv[r] = 1.0f / sm[r];

        f32x4 O[2];
        O[0] = (f32x4){0.f, 0.f, 0.f, 0.f};
        O[1] = (f32x4){0.f, 0.f, 0.f, 0.f};
        #pragma unroll
        for (int kc = 0; kc < 8; ++kc) {
            const bf16x8 ap = *(const bf16x8*)(Ps + (wv * 16 + L) * 264 + kc * 32 + qd * 8);
            #pragma unroll
            for (int jt = 0; jt < 2; ++jt) {
                const bf16x8 bv = *(const bf16x8*)(Vs + (jt * 16 + L) * 264 + kc * 32 + qd * 8);
                O[jt] = __builtin_amdgcn_mfma_f32_16x16x32_bf16(ap, bv, O[jt], 0, 0, 0);
            }
        }
        #pragma unroll
        for (int jt = 0; jt < 2; ++jt)
            #pragma unroll
            for (int r = 0; r < 4; ++r)
                Ot[(jt * 16 + L) * 72 + wv * 16 + qd * 4 + r] = f2bf(O[jt][r] * inv[r]);
        __syncthreads();

        {
            const int dd = t >> 3, cc = t & 7;
            bf16x8 ov = *(const bf16x8*)(Ot + dd * 72 + cc * 8);
            *(bf16x8*)(msgT + (size_t)b * 524288 +
                       ((size_t)((ks * HH + h) * DKK + dd)) * NN + q0 + cc * 8) = ov;
        }
        __syncthreads();
    }
}

// ---------------------------------------------------------------------------
extern "C" void kernel_launch(void* const* d_in, const int* in_sizes, int n_in,
                              void* d_out, int out_size, void* d_ws, size_t ws_size,
                              hipStream_t stream)
{
    const float* x         = (const float*)d_in[0];
    const float* dist      = (const float*)d_in[1];
    const float* dist_bar  = (const float*)d_in[2];
    const float* attn_bias = (const float*)d_in[3];
    const int*   mask      = (const int*)d_in[4];
    const float* Wq  = (const float*)d_in[6];  const float* bq  = (const float*)d_in[7];
    const float* Wk  = (const float*)d_in[8];  const float* bk  = (const float*)d_in[9];
    const float* Wv  = (const float*)d_in[10]; const float* bv  = (const float*)d_in[11];
    const float* W1  = (const float*)d_in[12]; const float* b1  = (const float*)d_in[13];
    const float* W2  = (const float*)d_in[14]; const float* b2  = (const float*)d_in[15];
    const float* g1  = (const float*)d_in[16]; const float* be1 = (const float*)d_in[17];
    const float* Wf1 = (const float*)d_in[18]; const float* bf1 = (const float*)d_in[19];
    const float* Wf2 = (const float*)d_in[20]; const float* bf2 = (const float*)d_in[21];
    const float* g2  = (const float*)d_in[22]; const float* be2 = (const float*)d_in[23];

    float* ws = (float*)d_ws;
    unsigned short* qkvb   = (unsigned short*)(ws + 0);          // bf16 [2048][1536]
    unsigned short* vT     = (unsigned short*)(ws + 1572864);    // bf16 [512][2048]
    unsigned short* xb     = (unsigned short*)(ws + 2097152);    // bf16 [2048][512]
    unsigned short* msgT   = (unsigned short*)(ws + 2621440);    // bf16 [8][2048][256] -> g3
    unsigned short* g3     = msgT;                               // bf16 [2048][2048]
    unsigned short* biasMs = (unsigned short*)(ws + 4718592);    // bf16 [2048][1024]
    float*          bqkv   = ws + 5767168;                       // f32 [1536]
    unsigned short* h1     = (unsigned short*)(ws + 5771264);    // bf16 [2048][512]
    float*          yb     = ws + 6295552;                       // f32 [2048][512]
    unsigned short* yb16   = (unsigned short*)(ws + 7344128);    // bf16 [2048][512]
    unsigned short* Wqkvt  = (unsigned short*)(ws + 7868416);    // bf16 [1536][512]
    unsigned short* W1t    = (unsigned short*)(ws + 8261632);    // bf16 [512][2048]
    unsigned short* W2t    = (unsigned short*)(ws + 8785920);    // bf16 [512][512]
    unsigned short* Wf1t   = (unsigned short*)(ws + 8916992);    // bf16 [2048][512]
    unsigned short* Wf2t   = (unsigned short*)(ws + 9441280);    // bf16 [512][2048]
    float*          h2     = ws + 9965568;                       // f32 [2048][512]
    float*          fb     = ws + 11014144;                      // f32 [2048][512]
    float*          outp   = (float*)d_out;

    const int M = BB * NN;  // 2048

    // 1) prep: weights, x, bqkv, biasMs
    prep_kernel<<<dim3(2048, 1, 10), dim3(256), 0, stream>>>(
        x, Wq, Wk, Wv, W1, W2, Wf1, Wf2, bq, bk, bv,
        attn_bias, mask, dist, dist_bar,
        xb, Wqkvt, W1t, W2t, Wf1t, Wf2t, bqkv, biasMs);

    // 2) fused QKV; v written transposed into vT
    mfma_gemm512<0, 1><<<dim3(12, 16), dim3(512), 0, stream>>>(
        xb, Wqkvt, bqkv, qkvb, vT, M, 1536, DD);

    // 3) 4-scale MFMA attention -> bf16 msgT (scrambled W1-input layout)
    attn_kernel<<<dim3(4, HH, BB), dim3(256), 0, stream>>>(qkvb, vT, biasMs, msgT);

    // 4) h1 = silu(msgT @ W1 + b1)   (8-wave 64² tile, 2 waves/SIMD)
    mfma_gemm64w8<1, 0><<<dim3(8, 32), dim3(512), 0, stream>>>(
        msgT, W1t, b1, h1, nullptr, M, DD, 2048);

    // 5) h2 = h1 @ W2 + b2 (fp32 out)
    mfma_gemm64w8<0, 1><<<dim3(8, 32), dim3(512), 0, stream>>>(
        h1, W2t, b2, nullptr, h2, M, DD, DD);

    // 6) y = LN(h2 + x)  (per-wave, barrier-free)
    ln_kernel<1><<<dim3(512), dim3(256), 0, stream>>>(h2, x, g1, be1, yb, yb16);

    // 7) g3 = gelu(y @ Wf1 + bf1)
    mfma_gemm512<2, 0><<<dim3(16, 16), dim3(512), 0, stream>>>(
        yb16, Wf1t, bf1, g3, nullptr, M, FFN_, DD);

    // 8) f = g3 @ Wf2 + bf2 (fp32 out, 8-wave 64² tile)
    mfma_gemm64w8<0, 1><<<dim3(8, 32), dim3(512), 0, stream>>>(
        g3, Wf2t, bf2, nullptr, fb, M, DD, 2048);

    // 9) out = LN(f + y)
    ln_kernel<0><<<dim3(512), dim3(256), 0, stream>>>(fb, yb, g2, be2, outp, nullptr);
}